// Round 1
// baseline (1511.489 us; speedup 1.0000x reference)
//
#include <hip/hip_runtime.h>

// Problem constants
#define LL 256   // sequence length
#define EE 64    // embed dim
#define HH 64    // hidden dim
#define GG 256   // 4*H gates
#define NN 2048  // B*S sequences
#define NS 8     // sequences per block

__device__ __forceinline__ float sigm(float x) {
    return 1.0f / (1.0f + __expf(-x));
}
__device__ __forceinline__ float tanh_fast(float x) {
    float t = fminf(fmaxf(2.0f * x, -30.0f), 30.0f);
    float e = __expf(t);
    return (e - 1.0f) / (e + 1.0f);
}

// One block = 8 sequences, one direction. Thread j owns gate column j
// (Wk[:,j], Wr[:,j] in 128 VGPRs). x,h broadcast from LDS; z via LDS.
__global__ __launch_bounds__(256, 2)
void bilstm_fused(const int* __restrict__ ids,
                  const float* __restrict__ embed,
                  const float* __restrict__ Wk_f, const float* __restrict__ Wr_f,
                  const float* __restrict__ b_f,
                  const float* __restrict__ Wk_b, const float* __restrict__ Wr_b,
                  const float* __restrict__ b_b,
                  float* __restrict__ out)
{
    const int dir = blockIdx.x >> 8;    // 0 = fwd, 1 = bwd
    const int grp = blockIdx.x & 255;   // sequence group
    const int n0  = grp * NS;
    const int tid = threadIdx.x;        // gate column j in [0,256)

    const float* Wk = dir ? Wk_b : Wk_f;
    const float* Wr = dir ? Wr_b : Wr_f;
    const float* bv = dir ? b_b  : b_f;

    __shared__ __align__(16) float s_x[NS][EE];   // 2 KB
    __shared__ __align__(16) float s_h[NS][HH];   // 2 KB
    __shared__ __align__(16) float s_z[NS][GG];   // 8 KB
    __shared__ int s_ids[NS][LL];                 // 8 KB

    // Stage ids for this block's 8 sequences (coalesced)
    for (int p = tid; p < NS * LL; p += 256) {
        int n = p >> 8;        // / LL
        int t = p & (LL - 1);
        s_ids[n][t] = ids[(size_t)(n0 + n) * LL + t];
    }
    // h0 = 0
    for (int p = tid; p < NS * HH; p += 256) {
        (&s_h[0][0])[p] = 0.0f;
    }

    // Weight columns into registers (coalesced loads, once)
    float wk[EE], wr[HH];
    #pragma unroll
    for (int k = 0; k < EE; ++k) wk[k] = Wk[k * GG + tid];
    #pragma unroll
    for (int k = 0; k < HH; ++k) wr[k] = Wr[k * GG + tid];
    const float bias = bv[tid];

    // cell state: thread owns pairs p=tid and p=tid+256 -> (n=p>>6, j=p&63)
    float c0 = 0.0f, c1 = 0.0f;

    __syncthreads();

    for (int ts = 0; ts < LL; ++ts) {
        const int t = dir ? (LL - 1 - ts) : ts;

        // gather embedding rows for this step (coalesced 256B per seq)
        #pragma unroll
        for (int q = 0; q < 2; ++q) {
            int p = tid + q * 256;
            int n = p >> 6, k = p & 63;
            int id = s_ids[n][t];
            s_x[n][k] = embed[(size_t)id * EE + k];
        }
        __syncthreads();   // A: s_x ready; prev-step s_h writes ordered too

        float acc[NS];
        #pragma unroll
        for (int n = 0; n < NS; ++n) acc[n] = bias;

        // z[n][tid] += sum_k x[n][k] * Wk[k][tid]
        #pragma unroll
        for (int k4 = 0; k4 < EE; k4 += 4) {
            #pragma unroll
            for (int n = 0; n < NS; ++n) {
                float4 xv = *(const float4*)(&s_x[n][k4]);
                acc[n] = fmaf(xv.x, wk[k4 + 0], acc[n]);
                acc[n] = fmaf(xv.y, wk[k4 + 1], acc[n]);
                acc[n] = fmaf(xv.z, wk[k4 + 2], acc[n]);
                acc[n] = fmaf(xv.w, wk[k4 + 3], acc[n]);
            }
        }
        // z[n][tid] += sum_k h[n][k] * Wr[k][tid]
        #pragma unroll
        for (int k4 = 0; k4 < HH; k4 += 4) {
            #pragma unroll
            for (int n = 0; n < NS; ++n) {
                float4 hv = *(const float4*)(&s_h[n][k4]);
                acc[n] = fmaf(hv.x, wr[k4 + 0], acc[n]);
                acc[n] = fmaf(hv.y, wr[k4 + 1], acc[n]);
                acc[n] = fmaf(hv.z, wr[k4 + 2], acc[n]);
                acc[n] = fmaf(hv.w, wr[k4 + 3], acc[n]);
            }
        }
        #pragma unroll
        for (int n = 0; n < NS; ++n) s_z[n][tid] = acc[n];
        __syncthreads();   // B: s_z ready

        // gate combine: thread handles 2 of the 512 (n, j) cells
        #pragma unroll
        for (int q = 0; q < 2; ++q) {
            int p = tid + q * 256;
            int n = p >> 6, j = p & 63;
            float zi = s_z[n][j];
            float zf = s_z[n][64 + j];
            float zg = s_z[n][128 + j];
            float zo = s_z[n][192 + j];
            float ig = sigm(zi);
            float fg = sigm(zf);
            float gg = tanh_fast(zg);
            float og = sigm(zo);
            float cc = q ? c1 : c0;
            cc = fg * cc + ig * gg;
            float hh = og * tanh_fast(cc);
            if (q) c1 = cc; else c0 = cc;
            s_h[n][j] = hh;
            out[((size_t)(n0 + n) * LL + t) * (2 * HH) + dir * HH + j] = hh;
        }
        // no barrier needed here: next iter's sync A orders s_h writes
        // (each thread: update -> x-load -> sync A -> matmul reads)
    }
}

extern "C" void kernel_launch(void* const* d_in, const int* in_sizes, int n_in,
                              void* d_out, int out_size, void* d_ws, size_t ws_size,
                              hipStream_t stream) {
    const int*   ids   = (const int*)d_in[0];
    const float* embed = (const float*)d_in[1];
    const float* Wk_f  = (const float*)d_in[2];
    const float* Wr_f  = (const float*)d_in[3];
    const float* b_f   = (const float*)d_in[4];
    const float* Wk_b  = (const float*)d_in[5];
    const float* Wr_b  = (const float*)d_in[6];
    const float* b_b   = (const float*)d_in[7];
    float* out = (float*)d_out;

    dim3 grid(512);   // 256 sequence-groups x 2 directions
    dim3 block(256);
    bilstm_fused<<<grid, block, 0, stream>>>(ids, embed,
                                             Wk_f, Wr_f, b_f,
                                             Wk_b, Wr_b, b_b,
                                             out);
}

// Round 3
// 567.587 us; speedup vs baseline: 2.6630x; 2.6630x over previous
//
#include <hip/hip_runtime.h>

#define LL 256   // sequence length
#define EE 64    // embed dim
#define HH 64    // hidden dim
#define GG 256   // 4*H gates
#define NSEQ 16  // sequences per block
#define ROWP 72  // padded LDS row stride in bf16 elems (144 B, 16B-aligned)

typedef __bf16 bf16_t;
typedef bf16_t bf16x8 __attribute__((ext_vector_type(8)));
typedef float  f32x4  __attribute__((ext_vector_type(4)));

union BfPack {
    unsigned short u[8];
    bf16x8 v;
};

__device__ __forceinline__ unsigned short f2bf(float f) {
    unsigned u = __float_as_uint(f);
    u = (u + 0x7FFFu + ((u >> 16) & 1u)) >> 16;   // RNE
    return (unsigned short)u;
}
__device__ __forceinline__ float sigm(float x) { return 1.0f / (1.0f + __expf(-x)); }
__device__ __forceinline__ float tanh_fast(float x) {
    float t = fminf(fmaxf(2.0f * x, -30.0f), 30.0f);
    float e = __expf(t);
    return (e - 1.0f) / (e + 1.0f);
}

// One block = 16 sequences, one direction. 4 waves; wave w owns gate columns
// j = w*16 + (lane&15) within each 64-wide gate group, so i/f/g/o for a given
// (seq, j) land in the same lane/register. Weights live in registers as MFMA
// B-fragments; h recurs through LDS (bf16, A-fragment layout, double-
// buffered); c stays in registers. One barrier per timestep.
__global__ __launch_bounds__(256, 1)
void bilstm_mfma(const int* __restrict__ ids,
                 const float* __restrict__ embed,
                 const float* __restrict__ Wk_f, const float* __restrict__ Wr_f,
                 const float* __restrict__ b_f,
                 const float* __restrict__ Wk_b, const float* __restrict__ Wr_b,
                 const float* __restrict__ b_b,
                 float* __restrict__ out)
{
    const int dir = blockIdx.x >> 7;    // 0 fwd, 1 bwd
    const int grp = blockIdx.x & 127;
    const int n0  = grp * NSEQ;
    const int tid  = threadIdx.x;
    const int w    = tid >> 6;
    const int lane = tid & 63;
    const int l15  = lane & 15;
    const int quad = lane >> 4;
    const int j    = w * 16 + l15;      // gate sub-index in [0,64)

    const float* Wk = dir ? Wk_b : Wk_f;
    const float* Wr = dir ? Wr_b : Wr_f;
    const float* bv = dir ? b_b  : b_f;

    __shared__ __align__(16) short s_x[2][NSEQ][ROWP];  // 4.5 KB
    __shared__ __align__(16) short s_h[2][NSEQ][ROWP];  // 4.5 KB
    __shared__ int s_ids[NSEQ][LL];                     // 16 KB

    // stage ids (coalesced)
    for (int p = tid; p < NSEQ * LL; p += 256) {
        int m = p >> 8, t = p & 255;
        s_ids[m][t] = ids[(size_t)(n0 + m) * LL + t];
    }
    // zero both h buffers (h0 = 0)
    for (int p = tid; p < 2 * NSEQ * ROWP; p += 256)
        (&s_h[0][0][0])[p] = 0;

    __syncthreads();   // s_ids/s_h visible to all waves (was MISSING -> fault)

    // B fragments (bf16) + bias C-fragments, register-resident all kernel.
    // B-frag layout: lane holds B[k = kc*32 + quad*8 + e][n = l15], e=0..7.
    bf16x8 bfrag[4][4];   // [gate tt][k-chunk]
    f32x4  biasC[4];
    #pragma unroll
    for (int tt = 0; tt < 4; ++tt) {
        int g = tt * 64 + j;            // global gate column
        float bb = bv[g];
        biasC[tt] = (f32x4){bb, bb, bb, bb};
        #pragma unroll
        for (int kc = 0; kc < 4; ++kc) {
            BfPack pk;
            #pragma unroll
            for (int e = 0; e < 8; ++e) {
                int kg = kc * 32 + quad * 8 + e;
                float v = (kg < 64) ? Wk[(size_t)kg * GG + g]
                                    : Wr[(size_t)(kg - 64) * GG + g];
                pk.u[e] = f2bf(v);
            }
            bfrag[tt][kc] = pk.v;
        }
    }

    // gather x for the first step into buffer 0
    {
        int t0 = dir ? (LL - 1) : 0;
        #pragma unroll
        for (int u = 0; u < 2; ++u) {
            int pp = tid + u * 256;
            int m = pp >> 5, ep = pp & 31;
            int id = s_ids[m][t0];
            float2 xv = *(const float2*)&embed[(size_t)id * EE + 2 * ep];
            unsigned pk = (unsigned)f2bf(xv.x) | ((unsigned)f2bf(xv.y) << 16);
            *(unsigned*)&s_x[0][m][2 * ep] = pk;
        }
    }
    __syncthreads();

    float c[4] = {0.f, 0.f, 0.f, 0.f};   // cell state for rows m = quad*4+r

    for (int ts = 0; ts < LL; ++ts) {
        const int t  = dir ? (LL - 1 - ts) : ts;
        const int rb = ts & 1, wb = (ts + 1) & 1;

        // issue prefetch of x_{ts+1} early (embed table is L2/L3-resident)
        float2 px0, px1;
        const int pm0 = tid >> 5, pe = tid & 31, pm1 = pm0 + 8;
        const bool pf = (ts + 1 < LL);
        if (pf) {
            int tn = dir ? (LL - 2 - ts) : (ts + 1);
            px0 = *(const float2*)&embed[(size_t)s_ids[pm0][tn] * EE + 2 * pe];
            px1 = *(const float2*)&embed[(size_t)s_ids[pm1][tn] * EE + 2 * pe];
        }

        // A fragments: lane reads A[m = l15][k = quad*8 .. +7] (ds_read_b128)
        bf16x8 ax0 = *(const bf16x8*)&s_x[rb][l15][quad * 8];
        bf16x8 ax1 = *(const bf16x8*)&s_x[rb][l15][32 + quad * 8];
        bf16x8 ah0 = *(const bf16x8*)&s_h[rb][l15][quad * 8];
        bf16x8 ah1 = *(const bf16x8*)&s_h[rb][l15][32 + quad * 8];

        // z = bias + x@Wk + h@Wr : 4 independent 4-deep MFMA chains
        f32x4 acc[4];
        #pragma unroll
        for (int tt = 0; tt < 4; ++tt) {
            f32x4 a = __builtin_amdgcn_mfma_f32_16x16x32_bf16(ax0, bfrag[tt][0], biasC[tt], 0, 0, 0);
            a = __builtin_amdgcn_mfma_f32_16x16x32_bf16(ax1, bfrag[tt][1], a, 0, 0, 0);
            a = __builtin_amdgcn_mfma_f32_16x16x32_bf16(ah0, bfrag[tt][2], a, 0, 0, 0);
            acc[tt] = __builtin_amdgcn_mfma_f32_16x16x32_bf16(ah1, bfrag[tt][3], a, 0, 0, 0);
        }

        // gate math in-register; C/D layout: row m = quad*4 + r, col = l15
        #pragma unroll
        for (int r = 0; r < 4; ++r) {
            float ig = sigm(acc[0][r]);
            float fg = sigm(acc[1][r]);
            float gg = tanh_fast(acc[2][r]);
            float og = sigm(acc[3][r]);
            c[r] = fg * c[r] + ig * gg;
            float hh = og * tanh_fast(c[r]);
            int m = quad * 4 + r;
            out[((size_t)(n0 + m) * LL + t) * (2 * HH) + dir * HH + j] = hh;
            s_h[wb][m][j] = (short)f2bf(hh);
        }

        // commit prefetched x into the write buffer
        if (pf) {
            unsigned pk0 = (unsigned)f2bf(px0.x) | ((unsigned)f2bf(px0.y) << 16);
            unsigned pk1 = (unsigned)f2bf(px1.x) | ((unsigned)f2bf(px1.y) << 16);
            *(unsigned*)&s_x[wb][pm0][2 * pe] = pk0;
            *(unsigned*)&s_x[wb][pm1][2 * pe] = pk1;
        }
        __syncthreads();   // orders wb-buffer writes before next step's reads
    }
}

extern "C" void kernel_launch(void* const* d_in, const int* in_sizes, int n_in,
                              void* d_out, int out_size, void* d_ws, size_t ws_size,
                              hipStream_t stream) {
    const int*   ids   = (const int*)d_in[0];
    const float* embed = (const float*)d_in[1];
    const float* Wk_f  = (const float*)d_in[2];
    const float* Wr_f  = (const float*)d_in[3];
    const float* b_f   = (const float*)d_in[4];
    const float* Wk_b  = (const float*)d_in[5];
    const float* Wr_b  = (const float*)d_in[6];
    const float* b_b   = (const float*)d_in[7];
    float* out = (float*)d_out;

    dim3 grid(256);   // 128 seq-groups x 2 directions, 16 seqs each
    dim3 block(256);
    bilstm_mfma<<<grid, block, 0, stream>>>(ids, embed,
                                            Wk_f, Wr_f, b_f,
                                            Wk_b, Wr_b, b_b,
                                            out);
}